// Round 2
// baseline (518.531 us; speedup 1.0000x reference)
//
#include <hip/hip_runtime.h>
#include <stdint.h>

#define N_NODES_C 50000
#define N_EDGES_C 1000000
#define NODE_DIM_C 128
#define EDGE_DIM_C 64

typedef __attribute__((ext_vector_type(8))) short short8;
typedef __attribute__((ext_vector_type(4))) float floatx4;

__device__ __forceinline__ short f2bf(float f) {
    union { float f; uint32_t u; } v; v.f = f;
    uint32_t u = v.u;
    uint32_t r = (u + 0x7FFFu + ((u >> 16) & 1u)) >> 16;  // RNE
    return (short)r;
}

__device__ __forceinline__ float bf2f(short s) {
    union { uint32_t u; float f; } v;
    v.u = ((uint32_t)(uint16_t)s) << 16;
    return v.f;
}

__device__ __forceinline__ float gelu_tanh(float x) {
    // jax.nn.gelu (approximate=True) == x * sigmoid(1.5957691*(x + 0.044715 x^3))
    float u = x * x;
    float inner = x * (1.0f + 0.044715f * u);
    float z = 1.5957691216057308f * inner;
    float ez = __expf(-z);
    return x / (1.0f + ez);
}

// ---------------- Kernel 1: node projections -> bf16 xs, xt in workspace -------
__global__ __launch_bounds__(256) void node_proj_kernel(
    const float* __restrict__ x,
    const float* __restrict__ Ws, const float* __restrict__ bs,
    const float* __restrict__ Wt, const float* __restrict__ bt,
    ushort* __restrict__ xs, ushort* __restrict__ xt)
{
    __shared__ __align__(16) short ws_frag[4][4][64][8];
    __shared__ __align__(16) short wt_frag[4][4][64][8];

    const int tid = threadIdx.x;
    for (int eidx = tid; eidx < 1024; eidx += 256) {
        int t = eidx >> 8;
        int s = (eidx >> 6) & 3;
        int l = eidx & 63;
        int n = t * 16 + (l & 15);
        int kb = s * 32 + ((l >> 4) << 3);
        const float* wsr = Ws + n * NODE_DIM_C + kb;
        const float* wtr = Wt + n * NODE_DIM_C + kb;
#pragma unroll
        for (int i = 0; i < 8; ++i) {
            ws_frag[t][s][l][i] = f2bf(wsr[i]);
            wt_frag[t][s][l][i] = f2bf(wtr[i]);
        }
    }
    __syncthreads();

    const int wave = tid >> 6, lane = tid & 63;
    const int m = lane & 15, q = lane >> 4;
    const int base = blockIdx.x * 64 + wave * 16;
    const int arow = base + m;

    floatx4 accS[4], accT[4];
    const floatx4 zero = {0.f, 0.f, 0.f, 0.f};
#pragma unroll
    for (int t = 0; t < 4; ++t) { accS[t] = zero; accT[t] = zero; }

#pragma unroll
    for (int s = 0; s < 4; ++s) {
        short8 a;
        if (arow < N_NODES_C) {
            const float4* ap = (const float4*)(x + (size_t)arow * NODE_DIM_C + s * 32 + q * 8);
            float4 a0 = ap[0], a1 = ap[1];
            a[0] = f2bf(a0.x); a[1] = f2bf(a0.y); a[2] = f2bf(a0.z); a[3] = f2bf(a0.w);
            a[4] = f2bf(a1.x); a[5] = f2bf(a1.y); a[6] = f2bf(a1.z); a[7] = f2bf(a1.w);
        } else {
#pragma unroll
            for (int i = 0; i < 8; ++i) a[i] = 0;
        }
#pragma unroll
        for (int t = 0; t < 4; ++t) {
            short8 bS = *(const short8*)ws_frag[t][s][lane];
            short8 bT = *(const short8*)wt_frag[t][s][lane];
            accS[t] = __builtin_amdgcn_mfma_f32_16x16x32_bf16(a, bS, accS[t], 0, 0, 0);
            accT[t] = __builtin_amdgcn_mfma_f32_16x16x32_bf16(a, bT, accT[t], 0, 0, 0);
        }
    }

#pragma unroll
    for (int t = 0; t < 4; ++t) {
        int col = t * 16 + m;
        float bsv = bs[col], btv = bt[col];
#pragma unroll
        for (int r = 0; r < 4; ++r) {
            int n = base + q * 4 + r;
            if (n < N_NODES_C) {
                xs[(size_t)n * EDGE_DIM_C + col] = (ushort)f2bf(accS[t][r] + bsv);
                xt[(size_t)n * EDGE_DIM_C + col] = (ushort)f2bf(accT[t][r] + btv);
            }
        }
    }
}

// ---------------- Kernel 2: fused edge MLP --------------------------------------
__global__ __launch_bounds__(256, 3) void edge_mlp_kernel(
    const float* __restrict__ ea, const int* __restrict__ ei,
    const float* __restrict__ We, const float* __restrict__ be,
    const float* __restrict__ W1, const float* __restrict__ b1,
    const ushort* __restrict__ xs, const ushort* __restrict__ xt,
    float* __restrict__ out)
{
    __shared__ __align__(16) short we_frag[4][2][64][8];  // 8 KB
    __shared__ __align__(16) short w1_frag[4][2][64][8];  // 8 KB
    __shared__ __align__(16) short pbuf[4][16][72];       // gelu bf16 tile (C->A xform)
    __shared__ __align__(16) float gsum[4][16][68];       // gather sums / out staging

    const int tid = threadIdx.x;
    for (int eidx = tid; eidx < 512; eidx += 256) {
        int t = eidx >> 7;
        int s = (eidx >> 6) & 1;
        int l = eidx & 63;
        int n = t * 16 + (l & 15);
        int kb = s * 32 + ((l >> 4) << 3);
        const float* wer = We + n * EDGE_DIM_C + kb;
        const float* w1r = W1 + n * EDGE_DIM_C + kb;
#pragma unroll
        for (int i = 0; i < 8; ++i) {
            we_frag[t][s][l][i] = f2bf(wer[i]);
            w1_frag[t][s][l][i] = f2bf(w1r[i]);
        }
    }
    __syncthreads();

    const int wave = tid >> 6, lane = tid & 63;
    const int m = lane & 15, q = lane >> 4;     // MFMA roles
    const int g_r = lane >> 2, g_c = lane & 3;  // gather/store roles: row, 16-col group
    const int* __restrict__ src = ei;
    const int* __restrict__ tgt = ei + N_EDGES_C;

    float bev[4], b1v[4];
#pragma unroll
    for (int t = 0; t < 4; ++t) { bev[t] = be[t * 16 + m]; b1v[t] = b1[t * 16 + m]; }

    const floatx4 zero = {0.f, 0.f, 0.f, 0.f};
    const int nchunks = N_EDGES_C / 64;  // 15625, exact

    int chunk = blockIdx.x;
    // prefetch first indices (breaks idx->gather serial chain in-loop)
    int si = src[chunk * 64 + wave * 16 + g_r];
    int ti = tgt[chunk * 64 + wave * 16 + g_r];

    for (; chunk < nchunks; chunk += gridDim.x) {
        const int base = chunk * 64 + wave * 16;

        // --- issue gather loads immediately (independent of GEMM1) ---
        int sic = min(max(si, 0), N_NODES_C - 1);
        int tic = min(max(ti, 0), N_NODES_C - 1);
        const short8* xsp = (const short8*)(xs + (size_t)sic * EDGE_DIM_C + g_c * 16);
        const short8* xtp = (const short8*)(xt + (size_t)tic * EDGE_DIM_C + g_c * 16);
        short8 gs0 = xsp[0], gs1 = xsp[1];
        short8 gt0 = xtp[0], gt1 = xtp[1];

        // --- prefetch next chunk's indices ---
        {
            int en = min((chunk + (int)gridDim.x) * 64 + wave * 16 + g_r, N_EDGES_C - 1);
            si = src[en];
            ti = tgt[en];
        }

        // --- GEMM1: e1 = ea @ We^T (A straight from global) ---
        floatx4 acc[4];
#pragma unroll
        for (int t = 0; t < 4; ++t) acc[t] = zero;
#pragma unroll
        for (int s = 0; s < 2; ++s) {
            const float4* ap = (const float4*)(ea + (size_t)(base + m) * EDGE_DIM_C + s * 32 + q * 8);
            float4 a0 = ap[0], a1 = ap[1];
            short8 a;
            a[0] = f2bf(a0.x); a[1] = f2bf(a0.y); a[2] = f2bf(a0.z); a[3] = f2bf(a0.w);
            a[4] = f2bf(a1.x); a[5] = f2bf(a1.y); a[6] = f2bf(a1.z); a[7] = f2bf(a1.w);
#pragma unroll
            for (int t = 0; t < 4; ++t) {
                short8 b = *(const short8*)we_frag[t][s][lane];
                acc[t] = __builtin_amdgcn_mfma_f32_16x16x32_bf16(a, b, acc[t], 0, 0, 0);
            }
        }

        // --- gather sums -> LDS tile (wave-private, DS in-order: no barrier) ---
        {
            float* grow = &gsum[wave][g_r][g_c * 16];
            float4 s0, s1, s2, s3;
            s0.x = bf2f(gs0[0]) + bf2f(gt0[0]); s0.y = bf2f(gs0[1]) + bf2f(gt0[1]);
            s0.z = bf2f(gs0[2]) + bf2f(gt0[2]); s0.w = bf2f(gs0[3]) + bf2f(gt0[3]);
            s1.x = bf2f(gs0[4]) + bf2f(gt0[4]); s1.y = bf2f(gs0[5]) + bf2f(gt0[5]);
            s1.z = bf2f(gs0[6]) + bf2f(gt0[6]); s1.w = bf2f(gs0[7]) + bf2f(gt0[7]);
            s2.x = bf2f(gs1[0]) + bf2f(gt1[0]); s2.y = bf2f(gs1[1]) + bf2f(gt1[1]);
            s2.z = bf2f(gs1[2]) + bf2f(gt1[2]); s2.w = bf2f(gs1[3]) + bf2f(gt1[3]);
            s3.x = bf2f(gs1[4]) + bf2f(gt1[4]); s3.y = bf2f(gs1[5]) + bf2f(gt1[5]);
            s3.z = bf2f(gs1[6]) + bf2f(gt1[6]); s3.w = bf2f(gs1[7]) + bf2f(gt1[7]);
            ((float4*)grow)[0] = s0; ((float4*)grow)[1] = s1;
            ((float4*)grow)[2] = s2; ((float4*)grow)[3] = s3;
        }

        // --- epilogue 1: + be + gathersum, gelu, bf16 tile to LDS ---
#pragma unroll
        for (int t = 0; t < 4; ++t) {
            int col = t * 16 + m;
#pragma unroll
            for (int r = 0; r < 4; ++r) {
                int row = q * 4 + r;
                float c = acc[t][r] + bev[t] + gsum[wave][row][col];
                pbuf[wave][row][col] = f2bf(gelu_tanh(c));
            }
        }

        // --- GEMM2: out = gelu_e @ W1^T ---
        floatx4 acc2[4];
#pragma unroll
        for (int t = 0; t < 4; ++t) acc2[t] = zero;
#pragma unroll
        for (int s = 0; s < 2; ++s) {
            short8 a2 = *(const short8*)&pbuf[wave][m][s * 32 + q * 8];
#pragma unroll
            for (int t = 0; t < 4; ++t) {
                short8 b = *(const short8*)w1_frag[t][s][lane];
                acc2[t] = __builtin_amdgcn_mfma_f32_16x16x32_bf16(a2, b, acc2[t], 0, 0, 0);
            }
        }

        // --- stage acc2 (+b1) through gsum tile, then 4x contiguous float4 stores ---
#pragma unroll
        for (int t = 0; t < 4; ++t) {
#pragma unroll
            for (int r = 0; r < 4; ++r) {
                gsum[wave][q * 4 + r][t * 16 + m] = acc2[t][r] + b1v[t];
            }
        }
        {
            const float4* orow = (const float4*)&gsum[wave][g_r][g_c * 16];
            float4 o0 = orow[0], o1 = orow[1], o2 = orow[2], o3 = orow[3];
            float4* op = (float4*)(out + (size_t)(base + g_r) * EDGE_DIM_C + g_c * 16);
            op[0] = o0; op[1] = o1; op[2] = o2; op[3] = o3;
        }
    }
}

extern "C" void kernel_launch(void* const* d_in, const int* in_sizes, int n_in,
                              void* d_out, int out_size, void* d_ws, size_t ws_size,
                              hipStream_t stream) {
    const float* x   = (const float*)d_in[0];
    const int*   ei  = (const int*)d_in[1];
    const float* ea  = (const float*)d_in[2];
    const float* We  = (const float*)d_in[3];
    const float* be  = (const float*)d_in[4];
    const float* Ws  = (const float*)d_in[5];
    const float* bs  = (const float*)d_in[6];
    const float* Wt  = (const float*)d_in[7];
    const float* bt  = (const float*)d_in[8];
    const float* W1  = (const float*)d_in[9];
    const float* b1  = (const float*)d_in[10];
    float* out = (float*)d_out;

    ushort* xs = (ushort*)d_ws;                           // 50000*64 bf16 = 6.4 MB
    ushort* xt = xs + (size_t)N_NODES_C * EDGE_DIM_C;     // +6.4 MB

    dim3 blk(256);
    dim3 grid_nodes((N_NODES_C + 63) / 64);  // 782
    node_proj_kernel<<<grid_nodes, blk, 0, stream>>>(x, Ws, bs, Wt, bt, xs, xt);

    dim3 grid_edges(3125);  // 15625 chunks of 64 edges, 5 per block
    edge_mlp_kernel<<<grid_edges, blk, 0, stream>>>(ea, ei, We, be, W1, b1, xs, xt, out);
}